// Round 6
// baseline (521.042 us; speedup 1.0000x reference)
//
#include <hip/hip_runtime.h>

#define NGRAPHS  1024
#define NNODES   65536
#define SLOT     32
#define MAXSLOTS 3040   // sum ceil(c_i/32) <= (65536 + 1024*31)/32 = 3040

// Redundant in-block scan: 256 threads, counts[1024] ->
//   s_offs[0..1024]  exclusive node offsets (s_offs[1024] = 65536)
//   s_slot[0..1024]  exclusive slot offsets (s_slot[1024] = total slots)
__device__ inline void block_scan(const int* __restrict__ counts,
                                  int* s_offs, int* s_slot) {
    const int t = threadIdx.x;
    const int lane = t & 63, w = t >> 6;  // 4 waves
    const int4 cv = reinterpret_cast<const int4*>(counts)[t];
    const int c0 = cv.x, c1 = cv.y, c2 = cv.z, c3 = cv.w;
    const int s0 = (c0 + 31) >> 5, s1 = (c1 + 31) >> 5;
    const int s2 = (c2 + 31) >> 5, s3 = (c3 + 31) >> 5;
    const int lc = c0 + c1 + c2 + c3;
    const int ls = s0 + s1 + s2 + s3;
    int ic = lc, is = ls;  // inclusive wave scan of per-thread sums
    #pragma unroll
    for (int d = 1; d < 64; d <<= 1) {
        int cc = __shfl_up(ic, d);
        int ss = __shfl_up(is, d);
        if (lane >= d) { ic += cc; is += ss; }
    }
    __shared__ int wc[4], wsl[4];
    if (lane == 63) { wc[w] = ic; wsl[w] = is; }
    __syncthreads();
    int bc = 0, bs = 0;
    for (int i = 0; i < w; ++i) { bc += wc[i]; bs += wsl[i]; }
    const int ec = bc + ic - lc;  // exclusive before this thread's 4 graphs
    const int es = bs + is - ls;
    s_offs[4 * t + 0] = ec;
    s_offs[4 * t + 1] = ec + c0;
    s_offs[4 * t + 2] = ec + c0 + c1;
    s_offs[4 * t + 3] = ec + c0 + c1 + c2;
    s_slot[4 * t + 0] = es;
    s_slot[4 * t + 1] = es + s0;
    s_slot[4 * t + 2] = es + s0 + s1;
    s_slot[4 * t + 3] = es + s0 + s1 + s2;
    if (t == 255) { s_offs[1024] = ec + lc; s_slot[1024] = es + ls; }
    __syncthreads();
}

// Single fused kernel. Block b sums slot b (<=32 node rows).
//  - cnt<=32: finish in place (scale + LDS transpose + direct store).
//  - else: write raw partial, release-fence, arrive on arrive[g]; the LAST
//    arriving block of graph g acquires and does the combine itself.
// No second launch; ~2700 device atomics total (vs R1's 3M scattered ones).
__global__ __launch_bounds__(256, 8) void pool_kernel(const float4* __restrict__ f4,
                                                      const int* __restrict__ counts,
                                                      int* __restrict__ arrive,
                                                      float4* __restrict__ partials,
                                                      float4* __restrict__ out4) {
    __shared__ int s_offs[1025];
    __shared__ int s_slot[1025];
    __shared__ float s_trans[1024];
    __shared__ int s_old;
    const int t = threadIdx.x;
    block_scan(counts, s_offs, s_slot);

    const int b = blockIdx.x;
    if (b >= s_slot[1024]) return;

    // largest g with s_slot[g] <= b (LDS binary search, uniform)
    int lo = 0, hi = NGRAPHS - 1;
    while (lo < hi) {
        int mid = (lo + hi + 1) >> 1;
        if (s_slot[mid] <= b) lo = mid; else hi = mid - 1;
    }
    const int g = lo;
    const int k0 = s_slot[g], k1 = s_slot[g + 1];
    const int gs = s_offs[g], ge = s_offs[g + 1];
    const int cnt = ge - gs;
    const int s = gs + (b - k0) * SLOT;
    const int len = min(SLOT, ge - s);

    const float4* base = f4 + (size_t)s * 256 + t;
    float4 a0 = {0, 0, 0, 0}, a1 = {0, 0, 0, 0}, a2 = {0, 0, 0, 0}, a3 = {0, 0, 0, 0};

    int n = 0;
    for (; n + 8 <= len; n += 8) {
        const float4* q = base + (size_t)n * 256;
        float4 v0 = q[0],    v1 = q[256],  v2 = q[512],  v3 = q[768];
        float4 v4 = q[1024], v5 = q[1280], v6 = q[1536], v7 = q[1792];
        a0.x += v0.x; a0.y += v0.y; a0.z += v0.z; a0.w += v0.w;
        a1.x += v1.x; a1.y += v1.y; a1.z += v1.z; a1.w += v1.w;
        a2.x += v2.x; a2.y += v2.y; a2.z += v2.z; a2.w += v2.w;
        a3.x += v3.x; a3.y += v3.y; a3.z += v3.z; a3.w += v3.w;
        a0.x += v4.x; a0.y += v4.y; a0.z += v4.z; a0.w += v4.w;
        a1.x += v5.x; a1.y += v5.y; a1.z += v5.z; a1.w += v5.w;
        a2.x += v6.x; a2.y += v6.y; a2.z += v6.z; a2.w += v6.w;
        a3.x += v7.x; a3.y += v7.y; a3.z += v7.z; a3.w += v7.w;
    }
    if (n < len) {
        const int last = len - 1;
        #pragma unroll
        for (int j = 0; j < 8; ++j) {  // clamped: all 8 in flight
            const int idx = n + j;
            const float4 v = base[(size_t)min(idx, last) * 256];
            const float wgt = (idx < len) ? 1.0f : 0.0f;
            a0.x += v.x * wgt; a0.y += v.y * wgt; a0.z += v.z * wgt; a0.w += v.w * wgt;
        }
    }

    float4 a;
    a.x = (a0.x + a1.x) + (a2.x + a3.x);
    a.y = (a0.y + a1.y) + (a2.y + a3.y);
    a.z = (a0.z + a1.z) + (a2.z + a3.z);
    a.w = (a0.w + a1.w) + (a2.w + a3.w);

    if (cnt <= SLOT) {
        // whole graph in this slot: finish here
        const float inv = 1.0f / (float)cnt;
        float4 m = {a.x * inv, a.y * inv, a.z * inv, a.w * inv};
        reinterpret_cast<float4*>(s_trans)[t] = m;  // s_trans[i] = mean at flat i
        __syncthreads();
        float4 o;  // out o=4t+j -> value s_trans[j*256 + t]
        o.x = s_trans[t];
        o.y = s_trans[256 + t];
        o.z = s_trans[512 + t];
        o.w = s_trans[768 + t];
        out4[(size_t)g * 256 + t] = o;
        return;
    }

    // multi-slot: publish partial, arrive; last arriver combines
    partials[(size_t)b * 256 + t] = a;
    __threadfence();                       // release: partial visible device-wide
    if (t == 0) s_old = atomicAdd(&arrive[g], 1);
    __syncthreads();
    if (s_old != k1 - k0 - 1) return;      // not last
    __threadfence();                       // acquire: see all partials

    float4 acc = {0, 0, 0, 0};
    for (int k = k0; k < k1; k += 4) {
        #pragma unroll
        for (int j = 0; j < 4; ++j) {      // clamped: 4 loads in flight
            const int kk = min(k + j, k1 - 1);
            const float wgt = (k + j < k1) ? 1.0f : 0.0f;
            const float4 v = partials[(size_t)kk * 256 + t];
            acc.x += v.x * wgt; acc.y += v.y * wgt;
            acc.z += v.z * wgt; acc.w += v.w * wgt;
        }
    }

    const float inv = 1.0f / (float)cnt;
    float4 m = {acc.x * inv, acc.y * inv, acc.z * inv, acc.w * inv};
    __syncthreads();                       // s_trans reuse safety (paranoia)
    reinterpret_cast<float4*>(s_trans)[t] = m;
    __syncthreads();
    float4 o;
    o.x = s_trans[t];
    o.y = s_trans[256 + t];
    o.z = s_trans[512 + t];
    o.w = s_trans[768 + t];
    out4[(size_t)g * 256 + t] = o;
}

extern "C" void kernel_launch(void* const* d_in, const int* in_sizes, int n_in,
                              void* d_out, int out_size, void* d_ws, size_t ws_size,
                              hipStream_t stream) {
    const float* features = (const float*)d_in[0];
    const int* counts = (const int*)d_in[1];

    int* arrive = (int*)d_ws;                            // 1024 ints, zeroed per call
    float4* partials = (float4*)((char*)d_ws + 16384);   // <=3040 * 4 KiB

    hipMemsetAsync(arrive, 0, NGRAPHS * sizeof(int), stream);
    pool_kernel<<<MAXSLOTS, 256, 0, stream>>>((const float4*)features, counts,
                                              arrive, partials, (float4*)d_out);
}

// Round 7
// 52.732 us; speedup vs baseline: 9.8810x; 9.8810x over previous
//
#include <hip/hip_runtime.h>

#define NGRAPHS  1024
#define NNODES   65536
#define SLOT     32
#define MAXSLOTS 3040   // sum ceil(c_i/32) <= (65536 + 1024*31)/32 = 3040

// Redundant in-block scan: 256 threads, counts[1024] ->
//   s_offs[0..1024]  exclusive node offsets (s_offs[1024] = 65536)
//   s_slot[0..1024]  exclusive slot offsets (s_slot[1024] = total slots)
__device__ inline void block_scan(const int* __restrict__ counts,
                                  int* s_offs, int* s_slot) {
    const int t = threadIdx.x;
    const int lane = t & 63, w = t >> 6;  // 4 waves
    const int4 cv = reinterpret_cast<const int4*>(counts)[t];
    const int c0 = cv.x, c1 = cv.y, c2 = cv.z, c3 = cv.w;
    const int s0 = (c0 + 31) >> 5, s1 = (c1 + 31) >> 5;
    const int s2 = (c2 + 31) >> 5, s3 = (c3 + 31) >> 5;
    const int lc = c0 + c1 + c2 + c3;
    const int ls = s0 + s1 + s2 + s3;
    int ic = lc, is = ls;  // inclusive wave scan of per-thread sums
    #pragma unroll
    for (int d = 1; d < 64; d <<= 1) {
        int cc = __shfl_up(ic, d);
        int ss = __shfl_up(is, d);
        if (lane >= d) { ic += cc; is += ss; }
    }
    __shared__ int wc[4], wsl[4];
    if (lane == 63) { wc[w] = ic; wsl[w] = is; }
    __syncthreads();
    int bc = 0, bs = 0;
    for (int i = 0; i < w; ++i) { bc += wc[i]; bs += wsl[i]; }
    const int ec = bc + ic - lc;  // exclusive before this thread's 4 graphs
    const int es = bs + is - ls;
    s_offs[4 * t + 0] = ec;
    s_offs[4 * t + 1] = ec + c0;
    s_offs[4 * t + 2] = ec + c0 + c1;
    s_offs[4 * t + 3] = ec + c0 + c1 + c2;
    s_slot[4 * t + 0] = es;
    s_slot[4 * t + 1] = es + s0;
    s_slot[4 * t + 2] = es + s0 + s1;
    s_slot[4 * t + 3] = es + s0 + s1 + s2;
    if (t == 255) { s_offs[1024] = ec + lc; s_slot[1024] = es + ls; }
    __syncthreads();
}

// Block b sums slot b (<=32 node rows). Single-slot graphs (cnt<=32) are
// finished in place: scale + LDS transpose + direct d_out store. Multi-slot
// graphs store a raw 4 KiB partial; slot 0 also records desc[g]={k0,cnt}.
// NOTE (R5 lesson): do NOT fuse the combine in with __threadfence() —
// device-scope fences invalidate L2 mid-stream and collapsed HBM BW 25x.
__global__ __launch_bounds__(256, 8) void partial_kernel(const float4* __restrict__ f4,
                                                         const int* __restrict__ counts,
                                                         int2* __restrict__ desc,
                                                         float4* __restrict__ partials,
                                                         float4* __restrict__ out4) {
    __shared__ int s_offs[1025];
    __shared__ int s_slot[1025];
    __shared__ float s_trans[1024];
    const int t = threadIdx.x;
    block_scan(counts, s_offs, s_slot);

    const int b = blockIdx.x;
    if (b >= s_slot[1024]) return;

    // largest g with s_slot[g] <= b (LDS binary search, uniform)
    int lo = 0, hi = NGRAPHS - 1;
    while (lo < hi) {
        int mid = (lo + hi + 1) >> 1;
        if (s_slot[mid] <= b) lo = mid; else hi = mid - 1;
    }
    const int g = lo;
    const int k = b - s_slot[g];
    const int gs = s_offs[g], ge = s_offs[g + 1];
    const int cnt = ge - gs;
    const int s = gs + k * SLOT;
    const int len = min(SLOT, ge - s);
    if (k == 0 && t == 0) desc[g] = make_int2(b, cnt);

    const float4* base = f4 + (size_t)s * 256 + t;
    float4 a0 = {0, 0, 0, 0}, a1 = {0, 0, 0, 0}, a2 = {0, 0, 0, 0}, a3 = {0, 0, 0, 0};

    int n = 0;
    for (; n + 8 <= len; n += 8) {
        const float4* q = base + (size_t)n * 256;
        float4 v0 = q[0],    v1 = q[256],  v2 = q[512],  v3 = q[768];
        float4 v4 = q[1024], v5 = q[1280], v6 = q[1536], v7 = q[1792];
        a0.x += v0.x; a0.y += v0.y; a0.z += v0.z; a0.w += v0.w;
        a1.x += v1.x; a1.y += v1.y; a1.z += v1.z; a1.w += v1.w;
        a2.x += v2.x; a2.y += v2.y; a2.z += v2.z; a2.w += v2.w;
        a3.x += v3.x; a3.y += v3.y; a3.z += v3.z; a3.w += v3.w;
        a0.x += v4.x; a0.y += v4.y; a0.z += v4.z; a0.w += v4.w;
        a1.x += v5.x; a1.y += v5.y; a1.z += v5.z; a1.w += v5.w;
        a2.x += v6.x; a2.y += v6.y; a2.z += v6.z; a2.w += v6.w;
        a3.x += v7.x; a3.y += v7.y; a3.z += v7.z; a3.w += v7.w;
    }
    if (n < len) {
        const int last = len - 1;
        #pragma unroll
        for (int j = 0; j < 8; ++j) {  // clamped: all 8 in flight
            const int idx = n + j;
            const float4 v = base[(size_t)min(idx, last) * 256];
            const float wgt = (idx < len) ? 1.0f : 0.0f;
            a0.x += v.x * wgt; a0.y += v.y * wgt; a0.z += v.z * wgt; a0.w += v.w * wgt;
        }
    }

    float4 a;
    a.x = (a0.x + a1.x) + (a2.x + a3.x);
    a.y = (a0.y + a1.y) + (a2.y + a3.y);
    a.z = (a0.z + a1.z) + (a2.z + a3.z);
    a.w = (a0.w + a1.w) + (a2.w + a3.w);

    if (cnt <= SLOT) {
        // whole graph in this slot: finish here (scale + transpose + store)
        const float inv = 1.0f / (float)cnt;
        float4 m = {a.x * inv, a.y * inv, a.z * inv, a.w * inv};
        reinterpret_cast<float4*>(s_trans)[t] = m;  // s_trans[i] = mean at flat i
        __syncthreads();
        float4 o;  // out o=4t+j -> value s_trans[j*256 + t]
        o.x = s_trans[t];
        o.y = s_trans[256 + t];
        o.z = s_trans[512 + t];
        o.w = s_trans[768 + t];
        out4[(size_t)g * 256 + t] = o;
    } else {
        partials[(size_t)b * 256 + t] = a;
    }
}

// One block per multi-slot graph: gather partials, scale, transpose, store.
__global__ __launch_bounds__(256) void combine_kernel(const float4* __restrict__ partials,
                                                      const int2* __restrict__ desc,
                                                      float4* __restrict__ out4) {
    const int g = blockIdx.x;
    const int2 dd = desc[g];
    const int cnt = dd.y;
    if (cnt <= SLOT) return;  // already written by partial_kernel
    const int t = threadIdx.x;
    const int k0 = dd.x;
    const int k1 = k0 + ((cnt + 31) >> 5);

    float4 a = {0, 0, 0, 0};
    for (int k = k0; k < k1; k += 4) {
        #pragma unroll
        for (int j = 0; j < 4; ++j) {  // clamped: 4 loads in flight
            const int kk = min(k + j, k1 - 1);
            const float wgt = (k + j < k1) ? 1.0f : 0.0f;
            const float4 v = partials[(size_t)kk * 256 + t];
            a.x += v.x * wgt; a.y += v.y * wgt; a.z += v.z * wgt; a.w += v.w * wgt;
        }
    }

    const float inv = 1.0f / (float)cnt;
    __shared__ float s_trans[1024];
    float4 m = {a.x * inv, a.y * inv, a.z * inv, a.w * inv};
    reinterpret_cast<float4*>(s_trans)[t] = m;
    __syncthreads();
    float4 o;
    o.x = s_trans[t];
    o.y = s_trans[256 + t];
    o.z = s_trans[512 + t];
    o.w = s_trans[768 + t];
    out4[(size_t)g * 256 + t] = o;
}

extern "C" void kernel_launch(void* const* d_in, const int* in_sizes, int n_in,
                              void* d_out, int out_size, void* d_ws, size_t ws_size,
                              hipStream_t stream) {
    const float* features = (const float*)d_in[0];
    const int* counts = (const int*)d_in[1];

    int2* desc = (int2*)d_ws;                            // 1024 * 8 B
    float4* partials = (float4*)((char*)d_ws + 16384);   // <=3040 * 4 KiB

    partial_kernel<<<MAXSLOTS, 256, 0, stream>>>((const float4*)features, counts,
                                                 desc, partials, (float4*)d_out);
    combine_kernel<<<NGRAPHS, 256, 0, stream>>>(partials, desc, (float4*)d_out);
}